// Round 8
// baseline (308.909 us; speedup 1.0000x reference)
//
#include <hip/hip_runtime.h>

#define N_L 8

typedef float v4f __attribute__((ext_vector_type(4)));

// ---------------------------------------------------------------------------
// Block (256 threads = 4 waves) sum reduction; result valid on thread 0.
// ---------------------------------------------------------------------------
__device__ __forceinline__ float block_reduce_sum(float v, float* smem) {
#pragma unroll
  for (int off = 32; off > 0; off >>= 1) v += __shfl_down(v, off, 64);
  int lane = threadIdx.x & 63;
  int wid  = threadIdx.x >> 6;
  if (lane == 0) smem[wid] = v;
  __syncthreads();
  if (threadIdx.x < 4) {
    v = smem[threadIdx.x];
    v += __shfl_down(v, 2, 64);
    v += __shfl_down(v, 1, 64);
  }
  return v;
}

// ---------------------------------------------------------------------------
// Materialize softmax table P (nV x 8 f32, 32B rows) into workspace.
// R6 lesson: divergent gathers want >=16B/lane; f32 32B rows (2x float4)
// are the measured-fastest layout (R1: 64us). Binary search on LDS fidx.
// Also zero-inits acc + done-counter for the gather kernel.
// ---------------------------------------------------------------------------
__global__ __launch_bounds__(256) void materialize_P(
    const float* __restrict__ tr, const float* __restrict__ fx,
    const int* __restrict__ fidx, int nF, int nV,
    float* __restrict__ P, double* __restrict__ acc,
    unsigned int* __restrict__ cnt) {
  __shared__ int sf[1024];
  const bool useLds = (nF <= 1024);
  if (useLds) {
    for (int j = threadIdx.x; j < nF; j += 256) sf[j] = fidx[j];
    __syncthreads();
  }
  int v = blockIdx.x * 256 + threadIdx.x;
  if (v == 0) { acc[0] = 0.0; cnt[0] = 0u; }
  if (v >= nV) return;

  const int* __restrict__ tab = useLds ? sf : fidx;
  int lo = 0, hi = nF;
  while (lo < hi) {
    int mid = (lo + hi) >> 1;
    if (tab[mid] < v) lo = mid + 1; else hi = mid;
  }
  const float* src = (lo < nF && tab[lo] == v) ? (fx + (size_t)lo * N_L)
                                               : (tr + (size_t)(v - lo) * N_L);
  float p[N_L];
  float4 a = *(const float4*)src;
  float4 b = *(const float4*)(src + 4);
  p[0] = a.x; p[1] = a.y; p[2] = a.z; p[3] = a.w;
  p[4] = b.x; p[5] = b.y; p[6] = b.z; p[7] = b.w;
  float m = p[0];
#pragma unroll
  for (int i = 1; i < N_L; ++i) m = fmaxf(m, p[i]);
  float s = 0.f;
#pragma unroll
  for (int i = 0; i < N_L; ++i) { p[i] = __expf(p[i] - m); s += p[i]; }
  float r = 1.0f / s;
  float4* dst = (float4*)(P + (size_t)v * N_L);
  dst[0] = make_float4(p[0] * r, p[1] * r, p[2] * r, p[3] * r);
  dst[1] = make_float4(p[4] * r, p[5] * r, p[6] * r, p[7] * r);
}

// ---------------------------------------------------------------------------
// Gather: exact R1 shape (measured best: thread-per-simplex, f32 rows,
// float4 loads) + nontemporal hint on row loads (table gets ~1-4% L1 hits
// anyway; if nt frees L1 miss-tracking resources, the ~14cyc/request wall
// moves; else neutral). Finalize fused via done-counter (validated R3/R5/R6).
// Pair term:   -(p.q)                        [+2/pair in cst]
// Triple term: -4*(d01+d02+d12) + (16/3)*T   [+8/tri in cst]
// ---------------------------------------------------------------------------
__device__ __forceinline__ v4f ldnt4(const float* p) {
  return __builtin_nontemporal_load((const v4f*)p);
}

__global__ __launch_bounds__(256) void gather_energy(
    const int* __restrict__ s1, int nP,
    const int* __restrict__ s2, int nT,
    const float* __restrict__ P, double* __restrict__ acc,
    unsigned int* __restrict__ cnt, int pairBlocks, int totalBlocks,
    float* __restrict__ out, double cst) {
  __shared__ float smem[4];
  float local = 0.f;

  if ((int)blockIdx.x < pairBlocks) {
    int i = blockIdx.x * 256 + threadIdx.x;
    if (i < nP) {
      int2 vv = ((const int2*)s1)[i];
      const float* A = P + (size_t)vv.x * N_L;
      const float* B = P + (size_t)vv.y * N_L;
      v4f a0 = ldnt4(A), a1 = ldnt4(A + 4);
      v4f b0 = ldnt4(B), b1 = ldnt4(B + 4);
      float d = a0.x * b0.x + a0.y * b0.y + a0.z * b0.z + a0.w * b0.w
              + a1.x * b1.x + a1.y * b1.y + a1.z * b1.z + a1.w * b1.w;
      local = -d;
    }
  } else {
    int i = (blockIdx.x - pairBlocks) * 256 + threadIdx.x;
    if (i < nT) {
      int v0 = s2[3 * i + 0];
      int v1 = s2[3 * i + 1];
      int v2 = s2[3 * i + 2];
      const float* A = P + (size_t)v0 * N_L;
      const float* B = P + (size_t)v1 * N_L;
      const float* C = P + (size_t)v2 * N_L;
      v4f a0 = ldnt4(A), a1 = ldnt4(A + 4);
      v4f b0 = ldnt4(B), b1 = ldnt4(B + 4);
      v4f c0 = ldnt4(C), c1 = ldnt4(C + 4);
      float pa[8] = {a0.x, a0.y, a0.z, a0.w, a1.x, a1.y, a1.z, a1.w};
      float pb[8] = {b0.x, b0.y, b0.z, b0.w, b1.x, b1.y, b1.z, b1.w};
      float pc[8] = {c0.x, c0.y, c0.z, c0.w, c1.x, c1.y, c1.z, c1.w};
      float d = 0.f, t3 = 0.f;
#pragma unroll
      for (int t = 0; t < N_L; ++t) {
        d  += pa[t] * pb[t] + pa[t] * pc[t] + pb[t] * pc[t];
        t3 += pa[t] * pb[t] * pc[t];
      }
      local = -4.0f * d + (16.0f / 3.0f) * t3;
    }
  }

  float bsum = block_reduce_sum(local, smem);
  if (threadIdx.x == 0) {
    atomicAdd(acc, (double)bsum);
    __threadfence();
    unsigned int done = atomicAdd(cnt, 1u);
    if (done == (unsigned int)(totalBlocks - 1)) {
      double total = atomicAdd(acc, 0.0);  // coherent read
      out[0] = (float)(cst + total);
    }
  }
}

// ---------------------------------------------------------------------------
// ws-too-small fallback: fully fused per-simplex softmax (round-0 path).
// ---------------------------------------------------------------------------
__global__ void init_acc(double* acc) { acc[0] = 0.0; }

__device__ __forceinline__ void load_P_row_fused(int v,
                                                 const float* __restrict__ tr,
                                                 const float* __restrict__ fx,
                                                 const int* __restrict__ fidx,
                                                 int nF, float p[N_L]) {
  int lo = 0, hi = nF;
  while (lo < hi) {
    int mid = (lo + hi) >> 1;
    if (fidx[mid] < v) lo = mid + 1; else hi = mid;
  }
  const float* src = (lo < nF && fidx[lo] == v) ? (fx + (size_t)lo * N_L)
                                                : (tr + (size_t)(v - lo) * N_L);
  float4 a = *(const float4*)src;
  float4 b = *(const float4*)(src + 4);
  p[0] = a.x; p[1] = a.y; p[2] = a.z; p[3] = a.w;
  p[4] = b.x; p[5] = b.y; p[6] = b.z; p[7] = b.w;
  float m = p[0];
#pragma unroll
  for (int i = 1; i < N_L; ++i) m = fmaxf(m, p[i]);
  float s = 0.f;
#pragma unroll
  for (int i = 0; i < N_L; ++i) { p[i] = __expf(p[i] - m); s += p[i]; }
  float r = 1.0f / s;
#pragma unroll
  for (int i = 0; i < N_L; ++i) p[i] *= r;
}

__global__ __launch_bounds__(256) void pair_kernel_fused(
    const int* __restrict__ simp, int n,
    const float* __restrict__ tr, const float* __restrict__ fx,
    const int* __restrict__ fidx, int nF, double* __restrict__ acc) {
  __shared__ float smem[4];
  int i = blockIdx.x * blockDim.x + threadIdx.x;
  float local = 0.f;
  if (i < n) {
    int2 vv = ((const int2*)simp)[i];
    float p[N_L], q[N_L];
    load_P_row_fused(vv.x, tr, fx, fidx, nF, p);
    load_P_row_fused(vv.y, tr, fx, fidx, nF, q);
    float d = 0.f;
#pragma unroll
    for (int t = 0; t < N_L; ++t) d += p[t] * q[t];
    local = -d;
  }
  float bsum = block_reduce_sum(local, smem);
  if (threadIdx.x == 0) atomicAdd(acc, (double)bsum);
}

__global__ __launch_bounds__(256) void triple_kernel_fused(
    const int* __restrict__ simp, int n,
    const float* __restrict__ tr, const float* __restrict__ fx,
    const int* __restrict__ fidx, int nF, double* __restrict__ acc) {
  __shared__ float smem[4];
  int i = blockIdx.x * blockDim.x + threadIdx.x;
  float local = 0.f;
  if (i < n) {
    int v0 = simp[3 * i + 0];
    int v1 = simp[3 * i + 1];
    int v2 = simp[3 * i + 2];
    float p[N_L], q[N_L], r[N_L];
    load_P_row_fused(v0, tr, fx, fidx, nF, p);
    load_P_row_fused(v1, tr, fx, fidx, nF, q);
    load_P_row_fused(v2, tr, fx, fidx, nF, r);
    float d01 = 0.f, d02 = 0.f, d12 = 0.f, t3 = 0.f;
#pragma unroll
    for (int t = 0; t < N_L; ++t) {
      d01 += p[t] * q[t];
      d02 += p[t] * r[t];
      d12 += q[t] * r[t];
      t3  += p[t] * q[t] * r[t];
    }
    local = -4.0f * (d01 + d02 + d12) + (16.0f / 3.0f) * t3;
  }
  float bsum = block_reduce_sum(local, smem);
  if (threadIdx.x == 0) atomicAdd(acc, (double)bsum);
}

__global__ void finalize(const double* __restrict__ acc,
                         float* __restrict__ out, double cst) {
  out[0] = (float)(cst + acc[0]);
}

extern "C" void kernel_launch(void* const* d_in, const int* in_sizes, int n_in,
                              void* d_out, int out_size, void* d_ws, size_t ws_size,
                              hipStream_t stream) {
  const float* tr   = (const float*)d_in[0];  // (N_V-N_FIXED, 8) f32
  const float* fx   = (const float*)d_in[1];  // (N_FIXED, 8) f32
  const int*   fidx = (const int*)d_in[2];    // (N_FIXED,) i32 (sorted)
  const int*   s1   = (const int*)d_in[3];    // (nP, 2) i32
  const int*   s2   = (const int*)d_in[4];    // (nT, 3) i32

  int nF = in_sizes[2];
  int nP = in_sizes[3] / 2;
  int nT = in_sizes[4] / 3;
  int nV = (in_sizes[0] + in_sizes[1]) / N_L;

  double*       acc = (double*)d_ws;                      // @0, 8B
  unsigned int* cnt = (unsigned int*)((char*)d_ws + 16);  // @16, 4B
  float*        P   = (float*)((char*)d_ws + 256);        // nV*8 f32, 32B rows
  float*        out = (float*)d_out;

  size_t need = 256 + (size_t)nV * N_L * sizeof(float);
  double cst = 2.0 * (double)nP + 8.0 * (double)nT;

  if (ws_size >= need) {
    materialize_P<<<(nV + 255) / 256, 256, 0, stream>>>(tr, fx, fidx, nF, nV, P, acc, cnt);
    int pairBlocks  = (nP + 255) / 256;
    int triBlocks   = (nT + 255) / 256;
    int totalBlocks = pairBlocks + triBlocks;
    gather_energy<<<totalBlocks, 256, 0, stream>>>(
        s1, nP, s2, nT, P, acc, cnt, pairBlocks, totalBlocks, out, cst);
  } else {
    init_acc<<<1, 1, 0, stream>>>(acc);
    pair_kernel_fused<<<(nP + 255) / 256, 256, 0, stream>>>(s1, nP, tr, fx, fidx, nF, acc);
    triple_kernel_fused<<<(nT + 255) / 256, 256, 0, stream>>>(s2, nT, tr, fx, fidx, nF, acc);
    finalize<<<1, 1, 0, stream>>>(acc, out, cst);
  }
}

// Round 9
// 206.288 us; speedup vs baseline: 1.4975x; 1.4975x over previous
//
#include <hip/hip_runtime.h>

#define N_L 8

// ---------------------------------------------------------------------------
// Block (256 threads = 4 waves) sum reduction; result valid on thread 0.
// ---------------------------------------------------------------------------
__device__ __forceinline__ float block_reduce_sum(float v, float* smem) {
#pragma unroll
  for (int off = 32; off > 0; off >>= 1) v += __shfl_down(v, off, 64);
  int lane = threadIdx.x & 63;
  int wid  = threadIdx.x >> 6;
  if (lane == 0) smem[wid] = v;
  __syncthreads();
  if (threadIdx.x < 4) {
    v = smem[threadIdx.x];
    v += __shfl_down(v, 2, 64);
    v += __shfl_down(v, 1, 64);
  }
  return v;
}

// ---------------------------------------------------------------------------
// Materialize softmax table P (nV x 8 f32, 32B rows) into workspace.
// Measured rules: divergent gathers want >=16B/lane f32 rows (R1 64us best;
// 8B rows 2x slower R6; nt hint 3.5x slower R8 - bypasses cache, FETCH 29MB).
// Binary search on LDS-staged fidx. Zero-inits acc + done-counter.
// ---------------------------------------------------------------------------
__global__ __launch_bounds__(256) void materialize_P(
    const float* __restrict__ tr, const float* __restrict__ fx,
    const int* __restrict__ fidx, int nF, int nV,
    float* __restrict__ P, double* __restrict__ acc,
    unsigned int* __restrict__ cnt) {
  __shared__ int sf[1024];
  const bool useLds = (nF <= 1024);
  if (useLds) {
    for (int j = threadIdx.x; j < nF; j += 256) sf[j] = fidx[j];
    __syncthreads();
  }
  int v = blockIdx.x * 256 + threadIdx.x;
  if (v == 0) { acc[0] = 0.0; cnt[0] = 0u; }
  if (v >= nV) return;

  const int* __restrict__ tab = useLds ? sf : fidx;
  int lo = 0, hi = nF;
  while (lo < hi) {
    int mid = (lo + hi) >> 1;
    if (tab[mid] < v) lo = mid + 1; else hi = mid;
  }
  const float* src = (lo < nF && tab[lo] == v) ? (fx + (size_t)lo * N_L)
                                               : (tr + (size_t)(v - lo) * N_L);
  float p[N_L];
  float4 a = *(const float4*)src;
  float4 b = *(const float4*)(src + 4);
  p[0] = a.x; p[1] = a.y; p[2] = a.z; p[3] = a.w;
  p[4] = b.x; p[5] = b.y; p[6] = b.z; p[7] = b.w;
  float m = p[0];
#pragma unroll
  for (int i = 1; i < N_L; ++i) m = fmaxf(m, p[i]);
  float s = 0.f;
#pragma unroll
  for (int i = 0; i < N_L; ++i) { p[i] = __expf(p[i] - m); s += p[i]; }
  float r = 1.0f / s;
  float4* dst = (float4*)(P + (size_t)v * N_L);
  dst[0] = make_float4(p[0] * r, p[1] * r, p[2] * r, p[3] * r);
  dst[1] = make_float4(p[4] * r, p[5] * r, p[6] * r, p[7] * r);
}

// ---------------------------------------------------------------------------
// Gather: the measured-optimal R1 shape — thread-per-simplex, f32 32B rows,
// plain float4 loads. Limiter (established R1..R8): ~2.8M divergent row
// requests x ~14cyc/CU L1-miss-handling throughput => ~64us floor.
// Finalize fused via done-counter (validated R3/R5/R6).
// Pair term:   -(p.q)                        [+2/pair in cst]
// Triple term: -4*(d01+d02+d12) + (16/3)*T   [+8/tri in cst]
// ---------------------------------------------------------------------------
__global__ __launch_bounds__(256) void gather_energy(
    const int* __restrict__ s1, int nP,
    const int* __restrict__ s2, int nT,
    const float* __restrict__ P, double* __restrict__ acc,
    unsigned int* __restrict__ cnt, int pairBlocks, int totalBlocks,
    float* __restrict__ out, double cst) {
  __shared__ float smem[4];
  float local = 0.f;

  if ((int)blockIdx.x < pairBlocks) {
    int i = blockIdx.x * 256 + threadIdx.x;
    if (i < nP) {
      int2 vv = ((const int2*)s1)[i];
      const float4* A = (const float4*)(P + (size_t)vv.x * N_L);
      const float4* B = (const float4*)(P + (size_t)vv.y * N_L);
      float4 a0 = A[0], a1 = A[1];
      float4 b0 = B[0], b1 = B[1];
      float d = a0.x * b0.x + a0.y * b0.y + a0.z * b0.z + a0.w * b0.w
              + a1.x * b1.x + a1.y * b1.y + a1.z * b1.z + a1.w * b1.w;
      local = -d;
    }
  } else {
    int i = (blockIdx.x - pairBlocks) * 256 + threadIdx.x;
    if (i < nT) {
      int v0 = s2[3 * i + 0];
      int v1 = s2[3 * i + 1];
      int v2 = s2[3 * i + 2];
      const float4* A = (const float4*)(P + (size_t)v0 * N_L);
      const float4* B = (const float4*)(P + (size_t)v1 * N_L);
      const float4* C = (const float4*)(P + (size_t)v2 * N_L);
      float4 a0 = A[0], a1 = A[1];
      float4 b0 = B[0], b1 = B[1];
      float4 c0 = C[0], c1 = C[1];
      float pa[8] = {a0.x, a0.y, a0.z, a0.w, a1.x, a1.y, a1.z, a1.w};
      float pb[8] = {b0.x, b0.y, b0.z, b0.w, b1.x, b1.y, b1.z, b1.w};
      float pc[8] = {c0.x, c0.y, c0.z, c0.w, c1.x, c1.y, c1.z, c1.w};
      float d = 0.f, t3 = 0.f;
#pragma unroll
      for (int t = 0; t < N_L; ++t) {
        d  += pa[t] * pb[t] + pa[t] * pc[t] + pb[t] * pc[t];
        t3 += pa[t] * pb[t] * pc[t];
      }
      local = -4.0f * d + (16.0f / 3.0f) * t3;
    }
  }

  float bsum = block_reduce_sum(local, smem);
  if (threadIdx.x == 0) {
    atomicAdd(acc, (double)bsum);
    __threadfence();
    unsigned int done = atomicAdd(cnt, 1u);
    if (done == (unsigned int)(totalBlocks - 1)) {
      double total = atomicAdd(acc, 0.0);  // coherent read
      out[0] = (float)(cst + total);
    }
  }
}

// ---------------------------------------------------------------------------
// ws-too-small fallback: fully fused per-simplex softmax (round-0 path).
// ---------------------------------------------------------------------------
__global__ void init_acc(double* acc) { acc[0] = 0.0; }

__device__ __forceinline__ void load_P_row_fused(int v,
                                                 const float* __restrict__ tr,
                                                 const float* __restrict__ fx,
                                                 const int* __restrict__ fidx,
                                                 int nF, float p[N_L]) {
  int lo = 0, hi = nF;
  while (lo < hi) {
    int mid = (lo + hi) >> 1;
    if (fidx[mid] < v) lo = mid + 1; else hi = mid;
  }
  const float* src = (lo < nF && fidx[lo] == v) ? (fx + (size_t)lo * N_L)
                                                : (tr + (size_t)(v - lo) * N_L);
  float4 a = *(const float4*)src;
  float4 b = *(const float4*)(src + 4);
  p[0] = a.x; p[1] = a.y; p[2] = a.z; p[3] = a.w;
  p[4] = b.x; p[5] = b.y; p[6] = b.z; p[7] = b.w;
  float m = p[0];
#pragma unroll
  for (int i = 1; i < N_L; ++i) m = fmaxf(m, p[i]);
  float s = 0.f;
#pragma unroll
  for (int i = 0; i < N_L; ++i) { p[i] = __expf(p[i] - m); s += p[i]; }
  float r = 1.0f / s;
#pragma unroll
  for (int i = 0; i < N_L; ++i) p[i] *= r;
}

__global__ __launch_bounds__(256) void pair_kernel_fused(
    const int* __restrict__ simp, int n,
    const float* __restrict__ tr, const float* __restrict__ fx,
    const int* __restrict__ fidx, int nF, double* __restrict__ acc) {
  __shared__ float smem[4];
  int i = blockIdx.x * blockDim.x + threadIdx.x;
  float local = 0.f;
  if (i < n) {
    int2 vv = ((const int2*)simp)[i];
    float p[N_L], q[N_L];
    load_P_row_fused(vv.x, tr, fx, fidx, nF, p);
    load_P_row_fused(vv.y, tr, fx, fidx, nF, q);
    float d = 0.f;
#pragma unroll
    for (int t = 0; t < N_L; ++t) d += p[t] * q[t];
    local = -d;
  }
  float bsum = block_reduce_sum(local, smem);
  if (threadIdx.x == 0) atomicAdd(acc, (double)bsum);
}

__global__ __launch_bounds__(256) void triple_kernel_fused(
    const int* __restrict__ simp, int n,
    const float* __restrict__ tr, const float* __restrict__ fx,
    const int* __restrict__ fidx, int nF, double* __restrict__ acc) {
  __shared__ float smem[4];
  int i = blockIdx.x * blockDim.x + threadIdx.x;
  float local = 0.f;
  if (i < n) {
    int v0 = simp[3 * i + 0];
    int v1 = simp[3 * i + 1];
    int v2 = simp[3 * i + 2];
    float p[N_L], q[N_L], r[N_L];
    load_P_row_fused(v0, tr, fx, fidx, nF, p);
    load_P_row_fused(v1, tr, fx, fidx, nF, q);
    load_P_row_fused(v2, tr, fx, fidx, nF, r);
    float d01 = 0.f, d02 = 0.f, d12 = 0.f, t3 = 0.f;
#pragma unroll
    for (int t = 0; t < N_L; ++t) {
      d01 += p[t] * q[t];
      d02 += p[t] * r[t];
      d12 += q[t] * r[t];
      t3  += p[t] * q[t] * r[t];
    }
    local = -4.0f * (d01 + d02 + d12) + (16.0f / 3.0f) * t3;
  }
  float bsum = block_reduce_sum(local, smem);
  if (threadIdx.x == 0) atomicAdd(acc, (double)bsum);
}

__global__ void finalize(const double* __restrict__ acc,
                         float* __restrict__ out, double cst) {
  out[0] = (float)(cst + acc[0]);
}

extern "C" void kernel_launch(void* const* d_in, const int* in_sizes, int n_in,
                              void* d_out, int out_size, void* d_ws, size_t ws_size,
                              hipStream_t stream) {
  const float* tr   = (const float*)d_in[0];  // (N_V-N_FIXED, 8) f32
  const float* fx   = (const float*)d_in[1];  // (N_FIXED, 8) f32
  const int*   fidx = (const int*)d_in[2];    // (N_FIXED,) i32 (sorted)
  const int*   s1   = (const int*)d_in[3];    // (nP, 2) i32
  const int*   s2   = (const int*)d_in[4];    // (nT, 3) i32

  int nF = in_sizes[2];
  int nP = in_sizes[3] / 2;
  int nT = in_sizes[4] / 3;
  int nV = (in_sizes[0] + in_sizes[1]) / N_L;

  double*       acc = (double*)d_ws;                      // @0, 8B
  unsigned int* cnt = (unsigned int*)((char*)d_ws + 16);  // @16, 4B
  float*        P   = (float*)((char*)d_ws + 256);        // nV*8 f32, 32B rows
  float*        out = (float*)d_out;

  size_t need = 256 + (size_t)nV * N_L * sizeof(float);
  double cst = 2.0 * (double)nP + 8.0 * (double)nT;

  if (ws_size >= need) {
    materialize_P<<<(nV + 255) / 256, 256, 0, stream>>>(tr, fx, fidx, nF, nV, P, acc, cnt);
    int pairBlocks  = (nP + 255) / 256;
    int triBlocks   = (nT + 255) / 256;
    int totalBlocks = pairBlocks + triBlocks;
    gather_energy<<<totalBlocks, 256, 0, stream>>>(
        s1, nP, s2, nT, P, acc, cnt, pairBlocks, totalBlocks, out, cst);
  } else {
    init_acc<<<1, 1, 0, stream>>>(acc);
    pair_kernel_fused<<<(nP + 255) / 256, 256, 0, stream>>>(s1, nP, tr, fx, fidx, nF, acc);
    triple_kernel_fused<<<(nT + 255) / 256, 256, 0, stream>>>(s2, nT, tr, fx, fidx, nF, acc);
    finalize<<<1, 1, 0, stream>>>(acc, out, cst);
  }
}

// Round 10
// 134.781 us; speedup vs baseline: 2.2919x; 1.5305x over previous
//
#include <hip/hip_runtime.h>

#define N_L 8

// ---------------------------------------------------------------------------
// Block (256 threads = 4 waves) sum reduction; result valid on thread 0.
// ---------------------------------------------------------------------------
__device__ __forceinline__ float block_reduce_sum(float v, float* smem) {
#pragma unroll
  for (int off = 32; off > 0; off >>= 1) v += __shfl_down(v, off, 64);
  int lane = threadIdx.x & 63;
  int wid  = threadIdx.x >> 6;
  if (lane == 0) smem[wid] = v;
  __syncthreads();
  if (threadIdx.x < 4) {
    v = smem[threadIdx.x];
    v += __shfl_down(v, 2, 64);
    v += __shfl_down(v, 1, 64);
  }
  return v;
}

// ---------------------------------------------------------------------------
// Materialize softmax table P (nV x 8 f32, 32B rows) into workspace.
// Scatter semantics: full[fixed_indices]=fixed; full[sorted complement]=
// trainable in order -> binary search v in fidx (LDS-staged).
// Also zero-inits acc + done-counter for the gather kernel.
// ---------------------------------------------------------------------------
__global__ __launch_bounds__(256) void materialize_P(
    const float* __restrict__ tr, const float* __restrict__ fx,
    const int* __restrict__ fidx, int nF, int nV,
    float* __restrict__ P, double* __restrict__ acc,
    unsigned int* __restrict__ cnt) {
  __shared__ int sf[1024];
  const bool useLds = (nF <= 1024);
  if (useLds) {
    for (int j = threadIdx.x; j < nF; j += 256) sf[j] = fidx[j];
    __syncthreads();
  }
  int v = blockIdx.x * 256 + threadIdx.x;
  if (v == 0) { acc[0] = 0.0; cnt[0] = 0u; }
  if (v >= nV) return;

  const int* __restrict__ tab = useLds ? sf : fidx;
  int lo = 0, hi = nF;
  while (lo < hi) {
    int mid = (lo + hi) >> 1;
    if (tab[mid] < v) lo = mid + 1; else hi = mid;
  }
  const float* src = (lo < nF && tab[lo] == v) ? (fx + (size_t)lo * N_L)
                                               : (tr + (size_t)(v - lo) * N_L);
  float p[N_L];
  float4 a = *(const float4*)src;
  float4 b = *(const float4*)(src + 4);
  p[0] = a.x; p[1] = a.y; p[2] = a.z; p[3] = a.w;
  p[4] = b.x; p[5] = b.y; p[6] = b.z; p[7] = b.w;
  float m = p[0];
#pragma unroll
  for (int i = 1; i < N_L; ++i) m = fmaxf(m, p[i]);
  float s = 0.f;
#pragma unroll
  for (int i = 0; i < N_L; ++i) { p[i] = __expf(p[i] - m); s += p[i]; }
  float r = 1.0f / s;
  float4* dst = (float4*)(P + (size_t)v * N_L);
  dst[0] = make_float4(p[0] * r, p[1] * r, p[2] * r, p[3] * r);
  dst[1] = make_float4(p[4] * r, p[5] * r, p[6] * r, p[7] * r);
}

// ---------------------------------------------------------------------------
// Gather: thread-per-simplex with G-way batching (measured-best config:
// 133.28us total, Round-5 bench). Batching keeps block count ~1564, which
// makes the fused done-counter finalize safe (R9 lesson: fence+same-line
// atomics at 4688 blocks cost +77us; at 1564 blocks they are noise).
// All index loads issue first, then ALL row loads (independent, one waitcnt
// group), then compute. Tails are branch-free: clamp index, mask weight.
// Pair term:   -(p.q)                        [+2/pair in cst]
// Triple term: -4*(d01+d02+d12) + (16/3)*T   [+8/tri in cst]
// Limiter (established R1..R9): ~2.8M divergent unique-line row touches x
// ~14cyc/CU L1-miss-handling throughput => ~64-70us gather floor,
// insensitive to occupancy/ILP/bytes/residency.
// ---------------------------------------------------------------------------
#define BP 4   // pairs per thread
#define BT 2   // triples per thread

__global__ __launch_bounds__(256) void gather_energy(
    const int* __restrict__ s1, int nP,
    const int* __restrict__ s2, int nT,
    const float* __restrict__ P, double* __restrict__ acc,
    unsigned int* __restrict__ cnt, int pairBlocks, int totalBlocks,
    float* __restrict__ out, double cst) {
  __shared__ float smem[4];
  float local = 0.f;

  if ((int)blockIdx.x < pairBlocks) {
    const int2* __restrict__ s1v = (const int2*)s1;
    int base = blockIdx.x * (256 * BP) + threadIdx.x;
    int2  vv[BP];
    float w[BP];
#pragma unroll
    for (int u = 0; u < BP; ++u) {
      int i  = base + u * 256;
      int ii = min(i, nP - 1);
      w[u]   = (i < nP) ? 1.0f : 0.0f;
      vv[u]  = s1v[ii];
    }
    float4 a0[BP], a1[BP], b0[BP], b1[BP];
#pragma unroll
    for (int u = 0; u < BP; ++u) {
      const float4* A = (const float4*)(P + (size_t)vv[u].x * N_L);
      const float4* B = (const float4*)(P + (size_t)vv[u].y * N_L);
      a0[u] = A[0]; a1[u] = A[1];
      b0[u] = B[0]; b1[u] = B[1];
    }
#pragma unroll
    for (int u = 0; u < BP; ++u) {
      float d = a0[u].x * b0[u].x + a0[u].y * b0[u].y
              + a0[u].z * b0[u].z + a0[u].w * b0[u].w
              + a1[u].x * b1[u].x + a1[u].y * b1[u].y
              + a1[u].z * b1[u].z + a1[u].w * b1[u].w;
      local -= w[u] * d;
    }
  } else {
    int base = (blockIdx.x - pairBlocks) * (256 * BT) + threadIdx.x;
    int   v0[BT], v1[BT], v2[BT];
    float w[BT];
#pragma unroll
    for (int u = 0; u < BT; ++u) {
      int i  = base + u * 256;
      int ii = min(i, nT - 1);
      w[u]   = (i < nT) ? 1.0f : 0.0f;
      v0[u] = s2[3 * ii + 0];
      v1[u] = s2[3 * ii + 1];
      v2[u] = s2[3 * ii + 2];
    }
    float4 a0[BT], a1[BT], b0[BT], b1[BT], c0[BT], c1[BT];
#pragma unroll
    for (int u = 0; u < BT; ++u) {
      const float4* A = (const float4*)(P + (size_t)v0[u] * N_L);
      const float4* B = (const float4*)(P + (size_t)v1[u] * N_L);
      const float4* C = (const float4*)(P + (size_t)v2[u] * N_L);
      a0[u] = A[0]; a1[u] = A[1];
      b0[u] = B[0]; b1[u] = B[1];
      c0[u] = C[0]; c1[u] = C[1];
    }
#pragma unroll
    for (int u = 0; u < BT; ++u) {
      float pa[8] = {a0[u].x, a0[u].y, a0[u].z, a0[u].w, a1[u].x, a1[u].y, a1[u].z, a1[u].w};
      float pb[8] = {b0[u].x, b0[u].y, b0[u].z, b0[u].w, b1[u].x, b1[u].y, b1[u].z, b1[u].w};
      float pc[8] = {c0[u].x, c0[u].y, c0[u].z, c0[u].w, c1[u].x, c1[u].y, c1[u].z, c1[u].w};
      float d01 = 0.f, d02 = 0.f, d12 = 0.f, t3 = 0.f;
#pragma unroll
      for (int t = 0; t < N_L; ++t) {
        d01 += pa[t] * pb[t];
        d02 += pa[t] * pc[t];
        d12 += pb[t] * pc[t];
        t3  += pa[t] * pb[t] * pc[t];
      }
      local += w[u] * (-4.0f * (d01 + d02 + d12) + (16.0f / 3.0f) * t3);
    }
  }

  float bsum = block_reduce_sum(local, smem);
  if (threadIdx.x == 0) {
    atomicAdd(acc, (double)bsum);
    __threadfence();
    unsigned int done = atomicAdd(cnt, 1u);
    if (done == (unsigned int)(totalBlocks - 1)) {
      double total = atomicAdd(acc, 0.0);  // coherent read
      out[0] = (float)(cst + total);
    }
  }
}

// ---------------------------------------------------------------------------
// ws-too-small fallback: fully fused per-simplex softmax (round-0 path).
// ---------------------------------------------------------------------------
__global__ void init_acc(double* acc) { acc[0] = 0.0; }

__device__ __forceinline__ void load_P_row_fused(int v,
                                                 const float* __restrict__ tr,
                                                 const float* __restrict__ fx,
                                                 const int* __restrict__ fidx,
                                                 int nF, float p[N_L]) {
  int lo = 0, hi = nF;
  while (lo < hi) {
    int mid = (lo + hi) >> 1;
    if (fidx[mid] < v) lo = mid + 1; else hi = mid;
  }
  const float* src = (lo < nF && fidx[lo] == v) ? (fx + (size_t)lo * N_L)
                                                : (tr + (size_t)(v - lo) * N_L);
  float4 a = *(const float4*)src;
  float4 b = *(const float4*)(src + 4);
  p[0] = a.x; p[1] = a.y; p[2] = a.z; p[3] = a.w;
  p[4] = b.x; p[5] = b.y; p[6] = b.z; p[7] = b.w;
  float m = p[0];
#pragma unroll
  for (int i = 1; i < N_L; ++i) m = fmaxf(m, p[i]);
  float s = 0.f;
#pragma unroll
  for (int i = 0; i < N_L; ++i) { p[i] = __expf(p[i] - m); s += p[i]; }
  float r = 1.0f / s;
#pragma unroll
  for (int i = 0; i < N_L; ++i) p[i] *= r;
}

__global__ __launch_bounds__(256) void pair_kernel_fused(
    const int* __restrict__ simp, int n,
    const float* __restrict__ tr, const float* __restrict__ fx,
    const int* __restrict__ fidx, int nF, double* __restrict__ acc) {
  __shared__ float smem[4];
  int i = blockIdx.x * blockDim.x + threadIdx.x;
  float local = 0.f;
  if (i < n) {
    int2 vv = ((const int2*)simp)[i];
    float p[N_L], q[N_L];
    load_P_row_fused(vv.x, tr, fx, fidx, nF, p);
    load_P_row_fused(vv.y, tr, fx, fidx, nF, q);
    float d = 0.f;
#pragma unroll
    for (int t = 0; t < N_L; ++t) d += p[t] * q[t];
    local = -d;
  }
  float bsum = block_reduce_sum(local, smem);
  if (threadIdx.x == 0) atomicAdd(acc, (double)bsum);
}

__global__ __launch_bounds__(256) void triple_kernel_fused(
    const int* __restrict__ simp, int n,
    const float* __restrict__ tr, const float* __restrict__ fx,
    const int* __restrict__ fidx, int nF, double* __restrict__ acc) {
  __shared__ float smem[4];
  int i = blockIdx.x * blockDim.x + threadIdx.x;
  float local = 0.f;
  if (i < n) {
    int v0 = simp[3 * i + 0];
    int v1 = simp[3 * i + 1];
    int v2 = simp[3 * i + 2];
    float p[N_L], q[N_L], r[N_L];
    load_P_row_fused(v0, tr, fx, fidx, nF, p);
    load_P_row_fused(v1, tr, fx, fidx, nF, q);
    load_P_row_fused(v2, tr, fx, fidx, nF, r);
    float d01 = 0.f, d02 = 0.f, d12 = 0.f, t3 = 0.f;
#pragma unroll
    for (int t = 0; t < N_L; ++t) {
      d01 += p[t] * q[t];
      d02 += p[t] * r[t];
      d12 += q[t] * r[t];
      t3  += p[t] * q[t] * r[t];
    }
    local = -4.0f * (d01 + d02 + d12) + (16.0f / 3.0f) * t3;
  }
  float bsum = block_reduce_sum(local, smem);
  if (threadIdx.x == 0) atomicAdd(acc, (double)bsum);
}

__global__ void finalize(const double* __restrict__ acc,
                         float* __restrict__ out, double cst) {
  out[0] = (float)(cst + acc[0]);
}

extern "C" void kernel_launch(void* const* d_in, const int* in_sizes, int n_in,
                              void* d_out, int out_size, void* d_ws, size_t ws_size,
                              hipStream_t stream) {
  const float* tr   = (const float*)d_in[0];  // (N_V-N_FIXED, 8) f32
  const float* fx   = (const float*)d_in[1];  // (N_FIXED, 8) f32
  const int*   fidx = (const int*)d_in[2];    // (N_FIXED,) i32 (sorted)
  const int*   s1   = (const int*)d_in[3];    // (nP, 2) i32
  const int*   s2   = (const int*)d_in[4];    // (nT, 3) i32

  int nF = in_sizes[2];
  int nP = in_sizes[3] / 2;
  int nT = in_sizes[4] / 3;
  int nV = (in_sizes[0] + in_sizes[1]) / N_L;

  double*       acc = (double*)d_ws;                      // @0, 8B
  unsigned int* cnt = (unsigned int*)((char*)d_ws + 16);  // @16, 4B
  float*        P   = (float*)((char*)d_ws + 256);        // nV*8 f32
  float*        out = (float*)d_out;

  size_t need = 256 + (size_t)nV * N_L * sizeof(float);
  double cst = 2.0 * (double)nP + 8.0 * (double)nT;

  if (ws_size >= need) {
    materialize_P<<<(nV + 255) / 256, 256, 0, stream>>>(tr, fx, fidx, nF, nV, P, acc, cnt);
    int pairBlocks  = (nP + 256 * BP - 1) / (256 * BP);
    int triBlocks   = (nT + 256 * BT - 1) / (256 * BT);
    int totalBlocks = pairBlocks + triBlocks;
    gather_energy<<<totalBlocks, 256, 0, stream>>>(
        s1, nP, s2, nT, P, acc, cnt, pairBlocks, totalBlocks, out, cst);
  } else {
    init_acc<<<1, 1, 0, stream>>>(acc);
    pair_kernel_fused<<<(nP + 255) / 256, 256, 0, stream>>>(s1, nP, tr, fx, fidx, nF, acc);
    triple_kernel_fused<<<(nT + 255) / 256, 256, 0, stream>>>(s2, nT, tr, fx, fidx, nF, acc);
    finalize<<<1, 1, 0, stream>>>(acc, out, cst);
  }
}